// Round 1
// baseline (1055.184 us; speedup 1.0000x reference)
//
#include <hip/hip_runtime.h>

#define T_TOK 65536
#define HDIM  1024
#define NSEG  64

typedef _Float16 half8  __attribute__((ext_vector_type(8)));
typedef float    f32x4  __attribute__((ext_vector_type(4)));
typedef float    f32x16 __attribute__((ext_vector_type(16)));

// ---- workspace layout (bytes) ----
#define WT_OFF   0ull                    // _Float16[1024*1024]: W^T, [col][k]
#define U0_OFF   2097152ull              // float[1024]: gamma*Wout[:,0]
#define U1_OFF   (U0_OFF + 4096ull)     // float[1024]: gamma*Wout[:,1]
#define CON_OFF  (U1_OFF + 4096ull)     // float[4]: G0,G1,Bt0,Bt1
#define ACC_OFF  (CON_OFF + 64ull)      // float[64*2] segment logit sums
#define CNT_OFF  (ACC_OFF + 512ull)     // int[64] segment counts

// ---------------------------------------------------------------------------
// k0: constants, u-vectors, segment counts (sorted ids -> boundary scan),
//     zero segment accumulators.
// ---------------------------------------------------------------------------
__global__ void prep_kernel(const float* __restrict__ gamma, const float* __restrict__ beta,
                            const float* __restrict__ wout, const int* __restrict__ segids,
                            float* __restrict__ u0, float* __restrict__ u1,
                            float* __restrict__ consts, float* __restrict__ segacc,
                            int* __restrict__ counts) {
    __shared__ int   starts[65];
    __shared__ float cacc[4];
    int tid = threadIdx.x;                       // blockDim = 1024 = HDIM
    if (tid < 128) segacc[tid] = 0.f;
    if (tid < 4)   cacc[tid]   = 0.f;
    if (tid == 0) { starts[0] = 0; starts[64] = T_TOK; }
    __syncthreads();

    float g  = gamma[tid], be = beta[tid];
    float w0 = wout[2 * tid], w1 = wout[2 * tid + 1];
    float a0 = g * w0, a1 = g * w1;
    u0[tid] = a0; u1[tid] = a1;
    float v[4] = {a0, a1, be * w0, be * w1};
#pragma unroll
    for (int q = 0; q < 4; ++q) {
        float x = v[q];
#pragma unroll
        for (int off = 32; off > 0; off >>= 1) x += __shfl_down(x, off, 64);
        if ((tid & 63) == 0) atomicAdd(&cacc[q], x);
    }
    // segment boundaries (ids sorted, all segments non-empty)
    for (int i = tid; i < T_TOK - 1; i += 1024) {
        int s0 = segids[i], s1 = segids[i + 1];
        if (s1 != s0) starts[s1] = i + 1;
    }
    __syncthreads();
    if (tid < 64) counts[tid] = starts[tid + 1] - starts[tid];
    if (tid < 4)  consts[tid] = cacc[tid];
}

// ---------------------------------------------------------------------------
// k1: W [k][col] fp32  ->  Wt [col][k] fp16   (LDS-tiled 64x64 transpose)
// ---------------------------------------------------------------------------
__global__ void wconv_kernel(const float* __restrict__ W, _Float16* __restrict__ Wt) {
    __shared__ float tile[64][65];
    int bx = blockIdx.x & 15;            // col tile
    int by = blockIdx.x >> 4;            // k tile
    int c0 = bx * 64, k0 = by * 64;
    int t  = threadIdx.x;                // 256 threads
    int kk = t >> 6, cc = t & 63;
#pragma unroll
    for (int i = 0; i < 16; ++i) {
        int kl = kk * 16 + i;
        tile[cc][kl] = W[(size_t)(k0 + kl) * HDIM + c0 + cc];   // coalesced
    }
    __syncthreads();
#pragma unroll
    for (int i = 0; i < 16; ++i) {
        int cl = kk * 16 + i;
        Wt[(size_t)(c0 + cl) * HDIM + k0 + cc] = (_Float16)tile[cl][cc]; // coalesced
    }
}

// ---------------------------------------------------------------------------
// k2: fused GEMM + residual + LN-functionals + segment partial reduce.
// 1024 blocks x 512 threads; block = 64 rows, full N=1024.
// A: fp32 global -> fp16 LDS fragment-chunks, staged per 256-wide K quarter.
// B: fp16 Wt, 16B contiguous per-lane register loads (L2-resident, no LDS).
// wave w covers cols [w*128, w*128+128): 2 row-tiles x 4 col-tiles of 32x32.
// ---------------------------------------------------------------------------
#define A_LDS 33280   // 32 khalf-rows * (64 chunks + 1 pad chunk) * 16B

__global__ __launch_bounds__(512, 2) void gemm_kernel(
    const float* __restrict__ A, const float* __restrict__ R,
    const float* __restrict__ bdense, const _Float16* __restrict__ Wt,
    const float* __restrict__ u0g, const float* __restrict__ u1g,
    const float* __restrict__ consts, const int* __restrict__ segids,
    float* __restrict__ segacc) {
    __shared__ __align__(16) char smem[A_LDS + 512 + 256];
    int tid  = threadIdx.x;
    int lane = tid & 63, wave = tid >> 6;
    int ln = lane & 31, lh = lane >> 5;
    int rowBase = blockIdx.x * 64;
    int colB    = wave * 128;

    f32x16 acc[2][4];
#pragma unroll
    for (int tr = 0; tr < 2; ++tr)
#pragma unroll
        for (int tc = 0; tc < 4; ++tc)
#pragma unroll
            for (int i = 0; i < 16; ++i) acc[tr][tc][i] = 0.f;

    // B fragment base pointers: Wt[col][k], lane reads 8 halves at k = lh*8 + ...
    const _Float16* bq[4];
#pragma unroll
    for (int tc = 0; tc < 4; ++tc)
        bq[tc] = Wt + (size_t)(colB + tc * 32 + ln) * HDIM + lh * 8;

    int mloc0 = tid >> 5;    // staging: row group
    int khalf = tid & 31;    // staging: 8-wide k chunk within quarter

    for (int kq = 0; kq < 4; ++kq) {
        __syncthreads();     // previous quarter fully consumed
        // ---- stage A quarter: 64 rows x 256 k, fp32 -> fp16 chunks ----
#pragma unroll
        for (int i = 0; i < 4; ++i) {
            int mloc = mloc0 + i * 16;
            const float* src = A + (size_t)(rowBase + mloc) * HDIM + kq * 256 + khalf * 8;
            f32x4 a0 = *(const f32x4*)src;
            f32x4 a1 = *(const f32x4*)(src + 4);
            half8 s;
            s[0] = (_Float16)a0[0]; s[1] = (_Float16)a0[1];
            s[2] = (_Float16)a0[2]; s[3] = (_Float16)a0[3];
            s[4] = (_Float16)a1[0]; s[5] = (_Float16)a1[1];
            s[6] = (_Float16)a1[2]; s[7] = (_Float16)a1[3];
            *(half8*)(smem + khalf * 1040 + mloc * 16) = s;   // 1040B pitch: conflict-free
        }
        __syncthreads();
        // ---- K loop: 16 steps of K=16 ----
#pragma unroll
        for (int ks = 0; ks < 16; ++ks) {
            half8 afr[2], bfr[4];
#pragma unroll
            for (int tr = 0; tr < 2; ++tr)
                afr[tr] = *(const half8*)(smem + (ks * 2 + lh) * 1040 + (tr * 32 + ln) * 16);
#pragma unroll
            for (int tc = 0; tc < 4; ++tc)
                bfr[tc] = *(const half8*)(bq[tc] + kq * 256 + ks * 16);
#pragma unroll
            for (int tr = 0; tr < 2; ++tr)
#pragma unroll
                for (int tc = 0; tc < 4; ++tc)
                    acc[tr][tc] = __builtin_amdgcn_mfma_f32_32x32x16_f16(
                        afr[tr], bfr[tc], acc[tr][tc], 0, 0, 0);
        }
    }

    // ---- epilogue: h = acc + b + r ; reduce S1,S2,P0,P1 per row ----
    __syncthreads();
    float* red  = (float*)smem;                 // [4][64 rows][32 lanes]
#pragma unroll
    for (int i = 0; i < 16; ++i) red[tid + i * 512] = 0.f;
    float* sval = (float*)(smem + A_LDS);       // [64][2]
    int*   sseg = (int*)(smem + A_LDS + 512);   // [64]
    __syncthreads();

    float bv[4], u0v[4], u1v[4];
#pragma unroll
    for (int tc = 0; tc < 4; ++tc) {
        int c = colB + tc * 32 + ln;
        bv[tc] = bdense[c]; u0v[tc] = u0g[c]; u1v[tc] = u1g[c];
    }
#pragma unroll
    for (int tr = 0; tr < 2; ++tr)
#pragma unroll
        for (int reg = 0; reg < 16; ++reg) {
            int rIT   = (reg & 3) + 8 * (reg >> 2) + 4 * lh;  // C/D row map (m74/m101)
            int row64 = tr * 32 + rIT;
            size_t grow = (size_t)(rowBase + row64);
            float s1 = 0.f, s2 = 0.f, p0 = 0.f, p1 = 0.f;
#pragma unroll
            for (int tc = 0; tc < 4; ++tc) {
                float h = acc[tr][tc][reg] + bv[tc] + R[grow * HDIM + colB + tc * 32 + ln];
                s1 += h; s2 += h * h; p0 += h * u0v[tc]; p1 += h * u1v[tc];
            }
            atomicAdd(&red[row64 * 32 + ln], s1);
            atomicAdd(&red[2048 + row64 * 32 + ln], s2);
            atomicAdd(&red[4096 + row64 * 32 + ln], p0);
            atomicAdd(&red[6144 + row64 * 32 + ln], p1);
        }
    __syncthreads();
    if (tid < 64) {
        float s1 = 0.f, s2 = 0.f, p0 = 0.f, p1 = 0.f;
        for (int c = 0; c < 32; ++c) {
            s1 += red[tid * 32 + c];
            s2 += red[2048 + tid * 32 + c];
            p0 += red[4096 + tid * 32 + c];
            p1 += red[6144 + tid * 32 + c];
        }
        float mu  = s1 * (1.f / 1024.f);
        float var = s2 * (1.f / 1024.f) - mu * mu;
        float rsd = rsqrtf(var + 1e-12f);
        sval[tid * 2]     = rsd * (p0 - mu * consts[0]) + consts[2];
        sval[tid * 2 + 1] = rsd * (p1 - mu * consts[1]) + consts[3];
        sseg[tid] = segids[rowBase + tid];
    }
    __syncthreads();
    // segment-run combine within the 64 sorted rows; one atomic pair per run
    if (tid < 64) {
        int s = sseg[tid];
        if (tid == 63 || sseg[tid + 1] != s) {
            float a0 = 0.f, a1 = 0.f;
            int rr = tid;
            while (rr >= 0 && sseg[rr] == s) { a0 += sval[rr * 2]; a1 += sval[rr * 2 + 1]; --rr; }
            atomicAdd(&segacc[s * 2],     a0);
            atomicAdd(&segacc[s * 2 + 1], a1);
        }
    }
}

// ---------------------------------------------------------------------------
// k3: logits[b][l] = segacc[b][l] / count[b] + b_out[l]
// ---------------------------------------------------------------------------
__global__ void finalize_kernel(const float* __restrict__ segacc, const int* __restrict__ counts,
                                const float* __restrict__ bout, float* __restrict__ out) {
    int t = threadIdx.x;
    if (t < 128) {
        int s = t >> 1, l = t & 1;
        out[t] = segacc[t] / (float)counts[s] + bout[l];
    }
}

extern "C" void kernel_launch(void* const* d_in, const int* in_sizes, int n_in,
                              void* d_out, int out_size, void* d_ws, size_t ws_size,
                              hipStream_t stream) {
    const float* A      = (const float*)d_in[0];  // sequence_attention_embeddings [T,H]
    const float* R      = (const float*)d_in[1];  // sequence_embeddings [T,H]
    const float* Wd     = (const float*)d_in[2];  // W_dense [H,H]
    const float* bdense = (const float*)d_in[3];  // b_dense [H]
    const float* gamma  = (const float*)d_in[4];  // gamma [H]
    const float* beta   = (const float*)d_in[5];  // beta [H]
    const float* wout   = (const float*)d_in[6];  // W_out [H,2]
    const float* bout   = (const float*)d_in[7];  // b_out [2]
    const int*   segids = (const int*)d_in[8];    // segment_ids [T]
    float* out = (float*)d_out;

    char* ws = (char*)d_ws;
    _Float16* Wt  = (_Float16*)(ws + WT_OFF);
    float* u0     = (float*)(ws + U0_OFF);
    float* u1     = (float*)(ws + U1_OFF);
    float* consts = (float*)(ws + CON_OFF);
    float* segacc = (float*)(ws + ACC_OFF);
    int*   counts = (int*)(ws + CNT_OFF);

    prep_kernel<<<1, 1024, 0, stream>>>(gamma, beta, wout, segids, u0, u1, consts, segacc, counts);
    wconv_kernel<<<256, 256, 0, stream>>>(Wd, Wt);
    gemm_kernel<<<1024, 512, 0, stream>>>(A, R, bdense, Wt, u0, u1, consts, segids, segacc);
    finalize_kernel<<<1, 128, 0, stream>>>(segacc, counts, bout, out);
}